// Round 8
// baseline (167.736 us; speedup 1.0000x reference)
//
#include <hip/hip_runtime.h>
#include <hip/hip_bf16.h>

#define T_SEQ 1024
#define D_MOD 512
#define NHEAD 8
#define HDIM  64
#define R_DIM 512
#define BATCH 2

typedef __attribute__((ext_vector_type(8))) __bf16 bf16x8;
typedef __attribute__((ext_vector_type(4))) __bf16 bf16x4;
typedef __attribute__((ext_vector_type(4))) float f32x4;
typedef __attribute__((ext_vector_type(2))) float f32x2;

__device__ __forceinline__ float ldin(const void* p, size_t i, int bf) {
    if (bf) return __bfloat162float(((const __hip_bfloat16*)p)[i]);
    return ((const float*)p)[i];
}
__device__ __forceinline__ void stout(void* p, size_t i, int bf, float v) {
    if (bf) ((__hip_bfloat16*)p)[i] = __float2bfloat16(v);
    else    ((float*)p)[i] = v;
}

__device__ __forceinline__ float gelu_f(float x) {
    return 0.5f * x * (1.f + tanhf(0.7978845608028654f * (x + 0.044715f * x * x * x)));
}

__device__ __forceinline__ bf16x8 cvt8(float4 a, float4 b) {
    bf16x8 t;
    t[0]=(__bf16)a.x; t[1]=(__bf16)a.y; t[2]=(__bf16)a.z; t[3]=(__bf16)a.w;
    t[4]=(__bf16)b.x; t[5]=(__bf16)b.y; t[6]=(__bf16)b.z; t[7]=(__bf16)b.w;
    return t;
}

// ---------------- fused projection GEMMs + zero job (R7, unchanged) ----------
template<int BF>
__global__ __launch_bounds__(256) void mega_gemm(
    const void* __restrict__ x, const void* __restrict__ Mi,
    const void* __restrict__ stf, const void* __restrict__ Mf,
    const void* __restrict__ Wq, const void* __restrict__ bq,
    const void* __restrict__ Wk, const void* __restrict__ bk,
    const void* __restrict__ Wv, const void* __restrict__ bv,
    const void* __restrict__ Wg, const void* __restrict__ bg,
    __bf16* __restrict__ fu, __bf16* __restrict__ fphi,
    __bf16* __restrict__ fQ, __bf16* __restrict__ fKT,
    __bf16* __restrict__ fV, __bf16* __restrict__ fVT,
    __bf16* __restrict__ fG)
{
    constexpr int bf = BF;
    const int tid = threadIdx.x;
    const int z = blockIdx.z;
    const int m0 = blockIdx.y * 64;
    const int n0 = blockIdx.x * 64;

    __shared__ __align__(16) __bf16 As[64][40];
    __shared__ __align__(16) __bf16 Bs[2][64][40];
    const int wave = tid >> 6, lane = tid & 63;
    const int lm = lane & 15, kq = lane >> 4;
    const int mo = tid >> 2, ko = (tid & 3) * 8;

    if (z <= 1) {
        const void* Wp0 = (z == 0) ? Wq : Wv;
        const void* Wp1 = (z == 0) ? Wk : Wg;
        const void* bp0 = (z == 0) ? bq : bv;
        const void* bp1 = (z == 0) ? bk : bg;
        f32x4 acc[2][4] = {};
        const int cs = ((((ko >> 3) ^ (mo >> 3)) & 3) << 3);

        for (int k0 = 0; k0 < 512; k0 += 32) {
            if (k0) __syncthreads();
            if (bf) {
                *(bf16x8*)&As[mo][ko] =
                    *(const bf16x8*)((const __bf16*)x + (size_t)(m0 + mo) * 512 + k0 + ko);
            } else {
                const float* Af = (const float*)x + (size_t)(m0 + mo) * 512 + k0 + ko;
                *(bf16x8*)&As[mo][ko] = cvt8(*(const float4*)Af, *(const float4*)(Af + 4));
            }
            const size_t go = (size_t)(n0 + mo) * 512 + k0 + ko;
            if (bf) {
                *(bf16x8*)&Bs[0][mo][cs] = *(const bf16x8*)((const __bf16*)Wp0 + go);
                *(bf16x8*)&Bs[1][mo][cs] = *(const bf16x8*)((const __bf16*)Wp1 + go);
            } else {
                const float* B0 = (const float*)Wp0 + go;
                const float* B1 = (const float*)Wp1 + go;
                *(bf16x8*)&Bs[0][mo][cs] = cvt8(*(const float4*)B0, *(const float4*)(B0 + 4));
                *(bf16x8*)&Bs[1][mo][cs] = cvt8(*(const float4*)B1, *(const float4*)(B1 + 4));
            }
            __syncthreads();
            const bf16x8 a = *(const bf16x8*)&As[wave * 16 + lm][kq * 8];
            #pragma unroll
            for (int p = 0; p < 2; ++p) {
                #pragma unroll
                for (int nt = 0; nt < 4; ++nt) {
                    const int row = nt * 16 + lm;
                    const bf16x8 b = *(const bf16x8*)&Bs[p][row][(((kq ^ (row >> 3)) & 3) << 3)];
                    acc[p][nt] = __builtin_amdgcn_mfma_f32_16x16x32_bf16(a, b, acc[p][nt], 0, 0, 0);
                }
            }
        }
        #pragma unroll
        for (int p = 0; p < 2; ++p) {
            const void* bias = p ? bp1 : bp0;
            #pragma unroll
            for (int nt = 0; nt < 4; ++nt) {
                const int n = n0 + nt * 16 + lm;
                #pragma unroll
                for (int r2 = 0; r2 < 4; ++r2) {
                    const int m = m0 + wave * 16 + kq * 4 + r2;
                    float v = acc[p][nt][r2] + ldin(bias, (size_t)n, bf);
                    v = (z == 1 && p == 1) ? 1.f / (1.f + expf(-v)) : gelu_f(v);
                    const int b = m >> 10, t = m & 1023;
                    const int h = n >> 6,  pp = n & 63;
                    if (z == 0) {
                        if (p == 0) fQ[(size_t)m * 512 + n] = (__bf16)v;
                        else fKT[(((size_t)b * NHEAD + h) * 64 + pp) * T_SEQ + t] = (__bf16)v;
                    } else {
                        if (p == 0) {
                            fV[(size_t)m * 512 + n] = (__bf16)v;
                            fVT[(((size_t)b * NHEAD + h) * 64 + pp) * T_SEQ + t] = (__bf16)v;
                        } else {
                            fG[(size_t)m * 512 + n] = (__bf16)v;
                        }
                    }
                }
            }
        }
    } else if (z == 2) {
        // ---- job0: fu = x @ Mi ----
        f32x4 acc[4] = {};
        const int kk = tid >> 3, nn = (tid & 7) * 8;
        for (int k0 = 0; k0 < 512; k0 += 32) {
            if (k0) __syncthreads();
            if (bf) {
                *(bf16x8*)&As[mo][ko] =
                    *(const bf16x8*)((const __bf16*)x + (size_t)(m0 + mo) * 512 + k0 + ko);
            } else {
                const float* Af = (const float*)x + (size_t)(m0 + mo) * 512 + k0 + ko;
                *(bf16x8*)&As[mo][ko] = cvt8(*(const float4*)Af, *(const float4*)(Af + 4));
            }
            {
                const size_t off = (size_t)(k0 + kk) * 512 + n0 + nn;
                bf16x8 t;
                if (bf) {
                    t = *(const bf16x8*)((const __bf16*)Mi + off);
                } else {
                    const float* Bf = (const float*)Mi + off;
                    t = cvt8(*(const float4*)Bf, *(const float4*)(Bf + 4));
                }
                #pragma unroll
                for (int q = 0; q < 8; ++q) {
                    const int row = nn + q;
                    const int c = ((((kk >> 3) ^ (row >> 3)) & 3) << 3) | (kk & 7);
                    Bs[0][row][c] = t[q];
                }
            }
            __syncthreads();
            const bf16x8 a = *(const bf16x8*)&As[wave * 16 + lm][kq * 8];
            #pragma unroll
            for (int nt = 0; nt < 4; ++nt) {
                const int row = nt * 16 + lm;
                const bf16x8 b = *(const bf16x8*)&Bs[0][row][(((kq ^ (row >> 3)) & 3) << 3)];
                acc[nt] = __builtin_amdgcn_mfma_f32_16x16x32_bf16(a, b, acc[nt], 0, 0, 0);
            }
        }
        #pragma unroll
        for (int nt = 0; nt < 4; ++nt) {
            const int n = n0 + nt * 16 + lm;
            #pragma unroll
            for (int r2 = 0; r2 < 4; ++r2) {
                const int m = m0 + wave * 16 + kq * 4 + r2;
                fu[(size_t)m * 512 + n] = (__bf16)acc[nt][r2];
            }
        }
    } else {
        if (blockIdx.y >= 16) {
            // ---- zero f_w (4 MB) ----
            float4* zp = (float4*)(fphi + 524288);           // == f_w
            const int bid = (blockIdx.y - 16) * 8 + blockIdx.x;   // 0..127
            const float4 z4 = make_float4(0.f, 0.f, 0.f, 0.f);
            #pragma unroll
            for (int q = 0; q < 8; ++q)
                zp[(size_t)bid * 2048 + q * 256 + tid] = z4;
            return;
        }
        // ---- job5: fphi = stf @ Mf ----
        f32x4 acc[4] = {};
        const int kk = tid >> 3, nn = (tid & 7) * 8;
        {
            bf16x8 t;
            #pragma unroll
            for (int q = 0; q < 8; ++q) {
                const int k = ko + q;
                t[q] = (k < 24) ? (__bf16)ldin(stf, (size_t)(m0 + mo) * 24 + k, bf)
                                : (__bf16)0.f;
            }
            *(bf16x8*)&As[mo][ko] = t;
        }
        #pragma unroll
        for (int q = 0; q < 8; ++q) {
            const int row = nn + q;
            const int c = ((((kk >> 3) ^ (row >> 3)) & 3) << 3) | (kk & 7);
            Bs[0][row][c] = (kk < 24) ? (__bf16)ldin(Mf, (size_t)kk * 512 + n0 + row, bf)
                                      : (__bf16)0.f;
        }
        __syncthreads();
        const bf16x8 a = *(const bf16x8*)&As[wave * 16 + lm][kq * 8];
        #pragma unroll
        for (int nt = 0; nt < 4; ++nt) {
            const int row = nt * 16 + lm;
            const bf16x8 b = *(const bf16x8*)&Bs[0][row][(((kq ^ (row >> 3)) & 3) << 3)];
            acc[nt] = __builtin_amdgcn_mfma_f32_16x16x32_bf16(a, b, acc[nt], 0, 0, 0);
        }
        #pragma unroll
        for (int nt = 0; nt < 4; ++nt) {
            const int n = n0 + nt * 16 + lm;
            #pragma unroll
            for (int r2 = 0; r2 < 4; ++r2) {
                const int m = m0 + wave * 16 + kq * 4 + r2;
                fphi[(size_t)m * 512 + n] = (__bf16)acc[nt][r2];
            }
        }
    }
}

// ---------------- per-tile attention state (R7, unchanged) ----------
__global__ __launch_bounds__(256) void state_k(const __bf16* __restrict__ KT,
                                               const __bf16* __restrict__ VT,
                                               float* __restrict__ T)
{
    __shared__ __align__(16) __bf16 Kt[64][72];
    __shared__ __align__(16) __bf16 Vt[64][72];
    const int tid = threadIdx.x;
    const int ti = blockIdx.x, h = blockIdx.y, b = blockIdx.z;
    const int s0 = ti * 64;
    const int wave = tid >> 6, lane = tid & 63;
    const int lm = lane & 15, kq = lane >> 4;
    const size_t hb = (size_t)b * NHEAD + h;
    const __bf16* KTh = KT + hb * 64 * T_SEQ;
    const __bf16* VTh = VT + hb * 64 * T_SEQ;
    #pragma unroll
    for (int it = 0; it < 2; ++it) {
        const int n = it * 256 + tid;
        const int row = n >> 3, c0 = (n & 7) * 8;
        *(bf16x8*)&Kt[row][c0] = *(const bf16x8*)&KTh[(size_t)row * T_SEQ + s0 + c0];
        *(bf16x8*)&Vt[row][c0] = *(const bf16x8*)&VTh[(size_t)row * T_SEQ + s0 + c0];
    }
    __syncthreads();
    f32x4 acc[4] = {};
    #pragma unroll
    for (int ks = 0; ks < 2; ++ks) {
        const bf16x8 a = *(const bf16x8*)&Kt[wave * 16 + lm][ks * 32 + kq * 8];
        #pragma unroll
        for (int nt = 0; nt < 4; ++nt) {
            const bf16x8 bb = *(const bf16x8*)&Vt[nt * 16 + lm][ks * 32 + kq * 8];
            acc[nt] = __builtin_amdgcn_mfma_f32_16x16x32_bf16(a, bb, acc[nt], 0, 0, 0);
        }
    }
    float* Tt = T + (hb * 16 + ti) * 4096;
    #pragma unroll
    for (int nt = 0; nt < 4; ++nt) {
        const int p = nt * 16 + lm;
        #pragma unroll
        for (int r2 = 0; r2 < 4; ++r2) {
            const int n = wave * 16 + kq * 4 + r2;
            Tt[n * 64 + p] = acc[nt][r2];
        }
    }
}

// ---------------- conv (packed-fp32 this round) + linear-attention Y ---------
// Off-diag conv inner loop now uses v_pk_fma_f32 (VOP3P packed fp32, 2 FMA
// per inst, CDNA2+): acc pairs (2j,2j+1) consume ur pairs (k,k+1) with k
// always even (i-2e+14, all even terms) -> clean f32x2 packing, identical
// per-element summation order (bit-exact). Halves conv VALU issue count.
__global__ __launch_bounds__(256) void conv_attn_k(
    const __bf16* __restrict__ u, const __bf16* __restrict__ vphi,
    float* __restrict__ w,
    const __bf16* __restrict__ Q, const __bf16* __restrict__ KT,
    const __bf16* __restrict__ V, const float* __restrict__ T,
    __bf16* __restrict__ Yb)
{
    __shared__ __align__(16) unsigned char smem[49152];
    const int tid = threadIdx.x;
    const int z = blockIdx.z;

    if (z < 2) {
        int rem = blockIdx.x, ti = 0;
        while (rem >= ((ti + 4) >> 2)) { rem -= (ti + 4) >> 2; ++ti; }
        const int jlo = rem * 4;
        const int jhi = (jlo + 3 < ti) ? jlo + 3 : ti;
        const int t0 = ti * 64;
        float (*vs)[64] = (float (*)[64])smem;            // 16 KB
        float (*us)[64] = (float (*)[64])(smem + 16384);  // 32 KB
        const int rl = tid & 63, tg = tid >> 6;
        const int b = z;
        const int r0 = blockIdx.y * 64;
        const __bf16* ub = u + (size_t)b * T_SEQ * R_DIM;
        f32x2 acc2[8] = {};
        for (int j = jlo; j <= jhi; ++j) {
            if (j != jlo) __syncthreads();
            const int L0 = j * 64;
            const int W0 = t0 - L0 - 63;
            #pragma unroll
            for (int jj = 0; jj < 8; ++jj) {
                const int n = jj * 256 + tid;
                const int row = n >> 4, c4 = (n & 15) * 4;
                int s = W0 + row;
                s = s < 0 ? 0 : (s > T_SEQ - 1 ? T_SEQ - 1 : s);
                const bf16x4 t = *(const bf16x4*)&ub[(size_t)s * R_DIM + r0 + c4];
                *(float4*)&us[row][c4] =
                    make_float4((float)t[0], (float)t[1], (float)t[2], (float)t[3]);
            }
            #pragma unroll
            for (int jj = 0; jj < 4; ++jj) {
                const int n = jj * 256 + tid;
                const int row = n >> 4, c4 = (n & 15) * 4;
                const bf16x4 t = *(const bf16x4*)&vphi[(size_t)(L0 + row) * R_DIM + r0 + c4];
                *(float4*)&vs[row][c4] =
                    make_float4((float)t[0], (float)t[1], (float)t[2], (float)t[3]);
            }
            __syncthreads();
            if (j < ti) {
                #pragma unroll
                for (int g = 0; g < 4; ++g) {
                    const int wsmin = tg * 16 + 49 - 16 * g;
                    f32x2 ur2[15];
                    #pragma unroll
                    for (int m = 0; m < 15; ++m) {
                        ur2[m][0] = us[wsmin + 2 * m][rl];
                        ur2[m][1] = us[wsmin + 2 * m + 1][rl];
                    }
                    float vr[8];
                    #pragma unroll
                    for (int e = 0; e < 8; ++e) vr[e] = vs[16 * g + 2 * e][rl];
                    #pragma unroll
                    for (int e = 0; e < 8; ++e) {
                        f32x2 vv2; vv2[0] = vr[e]; vv2[1] = vr[e];
                        #pragma unroll
                        for (int jj = 0; jj < 8; ++jj)
                            asm("v_pk_fma_f32 %0, %1, %2, %0"
                                : "+v"(acc2[jj]) : "v"(ur2[jj - e + 7]), "v"(vv2));
                    }
                }
            } else {
                for (int l = 0; l < 64; l += 2) {
                    const float vv = vs[l][rl];
                    #pragma unroll
                    for (int i = 0; i < 16; ++i) {
                        const int srel = tg * 16 + i - l;
                        if (srel >= 0) acc2[i >> 1][i & 1] += vv * us[srel + 63][rl];
                    }
                }
            }
        }
        #pragma unroll
        for (int i = 0; i < 16; ++i)
            atomicAdd(&w[((size_t)b * T_SEQ + t0 + tg * 16 + i) * R_DIM + r0 + rl],
                      2.f * acc2[i >> 1][i & 1]);
    } else {
        const int ti = blockIdx.x;
        if (ti >= 16) return;
        const int t0 = ti * 64;
        __bf16 (*Qs)[72] = (__bf16 (*)[72])smem;
        __bf16 (*Vs)[72] = (__bf16 (*)[72])(smem + 9216);
        __bf16 (*Kt)[72] = (__bf16 (*)[72])(smem + 18432);
        __bf16 (*Sa)[72] = (__bf16 (*)[72])(smem + 27648);
        __bf16 (*PB)[72] = (__bf16 (*)[72])(smem + 36864);
        const int wave = tid >> 6, lane = tid & 63;
        const int lm = lane & 15, kq = lane >> 4;
        const int b = z - 2;
        const int h = blockIdx.y;
        const size_t hb = (size_t)b * NHEAD + h;
        const size_t cbase = ((size_t)b * T_SEQ) * D_MOD + h * HDIM;
        const __bf16* KTh = KT + hb * 64 * T_SEQ;

        #pragma unroll
        for (int it = 0; it < 2; ++it) {
            const int n = it * 256 + tid;
            const int row = n >> 3, c0 = (n & 7) * 8;
            *(bf16x8*)&Qs[row][c0] = *(const bf16x8*)&Q[cbase + (size_t)(t0 + row) * D_MOD + c0];
            *(bf16x8*)&Vs[row][c0] = *(const bf16x8*)&V[cbase + (size_t)(t0 + row) * D_MOD + c0];
            *(bf16x8*)&Kt[row][c0] = *(const bf16x8*)&KTh[(size_t)row * T_SEQ + t0 + c0];
        }
        {
            const int mo = tid >> 2, ko2 = (tid & 3) * 16;
            float ps[16] = {};
            const float* Tb = T + hb * 16 * 4096 + mo * 64 + ko2;
            for (int j = 0; j < ti; ++j) {
                const float* tj = Tb + (size_t)j * 4096;
                #pragma unroll
                for (int q = 0; q < 4; ++q) {
                    const float4 v = *(const float4*)(tj + q * 4);
                    ps[q*4+0] += v.x; ps[q*4+1] += v.y; ps[q*4+2] += v.z; ps[q*4+3] += v.w;
                }
            }
            bf16x8 t0v, t1v;
            #pragma unroll
            for (int q = 0; q < 8; ++q) { t0v[q] = (__bf16)ps[q]; t1v[q] = (__bf16)ps[8+q]; }
            *(bf16x8*)&PB[mo][ko2]     = t0v;
            *(bf16x8*)&PB[mo][ko2 + 8] = t1v;
        }
        __syncthreads();

        f32x4 sacc[4] = {};
        #pragma unroll
        for (int ks = 0; ks < 2; ++ks) {
            const bf16x8 a = *(const bf16x8*)&Qs[wave * 16 + lm][ks * 32 + kq * 8];
            #pragma unroll
            for (int nt = 0; nt < 4; ++nt) {
                const bf16x8 bb = *(const bf16x8*)&Vs[nt * 16 + lm][ks * 32 + kq * 8];
                sacc[nt] = __builtin_amdgcn_mfma_f32_16x16x32_bf16(a, bb, sacc[nt], 0, 0, 0);
            }
        }
        #pragma unroll
        for (int nt = 0; nt < 4; ++nt) {
            const int sl = nt * 16 + lm;
            #pragma unroll
            for (int r2 = 0; r2 < 4; ++r2) {
                const int tl = wave * 16 + kq * 4 + r2;
                float v = sacc[nt][r2];
                if (sl > tl) v = 0.f;
                Sa[tl][sl] = (__bf16)v;
            }
        }
        f32x4 accY[4] = {};
        #pragma unroll
        for (int ks = 0; ks < 2; ++ks) {
            const bf16x8 a = *(const bf16x8*)&Sa[wave * 16 + lm][ks * 32 + kq * 8];
            #pragma unroll
            for (int nt = 0; nt < 4; ++nt) {
                const bf16x8 bb = *(const bf16x8*)&Kt[nt * 16 + lm][ks * 32 + kq * 8];
                accY[nt] = __builtin_amdgcn_mfma_f32_16x16x32_bf16(a, bb, accY[nt], 0, 0, 0);
            }
        }
        if (ti) {
            #pragma unroll
            for (int ks = 0; ks < 2; ++ks) {
                const bf16x8 a = *(const bf16x8*)&Qs[wave * 16 + lm][ks * 32 + kq * 8];
                #pragma unroll
                for (int nt = 0; nt < 4; ++nt) {
                    const bf16x8 bb = *(const bf16x8*)&PB[nt * 16 + lm][ks * 32 + kq * 8];
                    accY[nt] = __builtin_amdgcn_mfma_f32_16x16x32_bf16(a, bb, accY[nt], 0, 0, 0);
                }
            }
        }
        #pragma unroll
        for (int nt = 0; nt < 4; ++nt) {
            const int nh = nt * 16 + lm;
            #pragma unroll
            for (int r2 = 0; r2 < 4; ++r2) {
                const int tl = wave * 16 + kq * 4 + r2;
                Yb[cbase + (size_t)(t0 + tl) * D_MOD + nh] = (__bf16)accY[nt][r2];
            }
        }
    }
}

// ---------------- LN row stats (unchanged) ----------
__global__ __launch_bounds__(256) void stats_k(const float* __restrict__ w,
                                               float* __restrict__ stats)
{
    const int tid = threadIdx.x;
    const int r = tid >> 4, c = tid & 15;
    const int row = blockIdx.x * 16 + r;
    const float* p = w + (size_t)row * R_DIM;
    float s = 0.f, ss = 0.f;
    #pragma unroll
    for (int q = 0; q < 8; ++q) {
        const float4 v = *(const float4*)(p + c * 4 + q * 64);
        s  += v.x + v.y + v.z + v.w;
        ss += v.x * v.x + v.y * v.y + v.z * v.z + v.w * v.w;
    }
    s  += __shfl_xor(s, 1, 64);  s  += __shfl_xor(s, 2, 64);
    s  += __shfl_xor(s, 4, 64);  s  += __shfl_xor(s, 8, 64);
    ss += __shfl_xor(ss, 1, 64); ss += __shfl_xor(ss, 2, 64);
    ss += __shfl_xor(ss, 4, 64); ss += __shfl_xor(ss, 8, 64);
    if (c == 0) {
        const float mu = s * (1.f / 512.f);
        float var = ss * (1.f / 512.f) - mu * mu;
        var = var < 0.f ? 0.f : var;
        stats[row * 2]     = mu;
        stats[row * 2 + 1] = rsqrtf(var + 1e-5f);
    }
}

// ---------------- final GEMM with fused LN + comb (unchanged) ----------------
template<int BF>
__global__ __launch_bounds__(256) void final_gemm(const __bf16* __restrict__ G,
                                                  const __bf16* __restrict__ Yf,
                                                  const float* __restrict__ Wf,
                                                  const float* __restrict__ stats,
                                                  const void* __restrict__ lnw,
                                                  const void* __restrict__ lnb,
                                                  const void* __restrict__ Wo,
                                                  const void* __restrict__ bo,
                                                  void* __restrict__ out)
{
    constexpr int bf = BF;
    __shared__ __align__(16) __bf16 sm[2][2 * 64 * 40];
    const int tid = threadIdx.x;
    const int wave = tid >> 6, lane = tid & 63;
    const int lm = lane & 15, kq = lane >> 4;
    const int mo = tid >> 2, ko = (tid & 3) * 8;
    const int m0 = blockIdx.y * 64, n0 = blockIdx.x * 64;

    const float2 st = *(const float2*)(stats + (size_t)(m0 + mo) * 2);
    const float mu = st.x, rs = st.y;

    bf16x8 pg, py, pw, pLg, pLb;
    float4 pv0, pv1, pw0, pw1, pLg0, pLg1, pLb0, pLb1;

    auto issue = [&](int k0) {
        const size_t off = (size_t)(m0 + mo) * 512 + k0 + ko;
        pg  = *(const bf16x8*)(G + off);
        py  = *(const bf16x8*)(Yf + off);
        pv0 = *(const float4*)(Wf + off); pv1 = *(const float4*)(Wf + off + 4);
        const size_t ob = (size_t)(n0 + mo) * 512 + k0 + ko;
        if (bf) {
            pw  = *(const bf16x8*)((const __bf16*)Wo + ob);
            pLg = *(const bf16x8*)((const __bf16*)lnw + k0 + ko);
            pLb = *(const bf16x8*)((const __bf16*)lnb + k0 + ko);
        } else {
            const float* Bf = (const float*)Wo + ob;
            pw0 = *(const float4*)Bf; pw1 = *(const float4*)(Bf + 4);
            const float* Lg = (const float*)lnw + k0 + ko;
            pLg0 = *(const float4*)Lg; pLg1 = *(const float4*)(Lg + 4);
            const float* Lb = (const float*)lnb + k0 + ko;
            pLb0 = *(const float4*)Lb; pLb1 = *(const float4*)(Lb + 4);
        }
    };
    auto commit = [&](int bi) {
        __bf16 (*As)[40] = (__bf16 (*)[40])sm[bi];
        __bf16 (*Bs)[40] = (__bf16 (*)[40])(sm[bi] + 64 * 40);
        const float wv[8] = {pv0.x,pv0.y,pv0.z,pv0.w,pv1.x,pv1.y,pv1.z,pv1.w};
        float gw[8], gb[8];
        if (bf) {
            #pragma unroll
            for (int q = 0; q < 8; ++q) { gw[q] = (float)pLg[q]; gb[q] = (float)pLb[q]; }
        } else {
            gw[0]=pLg0.x; gw[1]=pLg0.y; gw[2]=pLg0.z; gw[3]=pLg0.w;
            gw[4]=pLg1.x; gw[5]=pLg1.y; gw[6]=pLg1.z; gw[7]=pLg1.w;
            gb[0]=pLb0.x; gb[1]=pLb0.y; gb[2]=pLb0.z; gb[3]=pLb0.w;
            gb[4]=pLb1.x; gb[5]=pLb1.y; gb[6]=pLb1.z; gb[7]=pLb1.w;
        }
        bf16x8 t;
        #pragma unroll
        for (int q = 0; q < 8; ++q) {
            const float xt = (wv[q] - mu) * rs * gw[q] + gb[q];
            const float gg = (float)pg[q];
            t[q] = (__bf16)(gg * (float)py[q] + (1.f - gg) * xt);
        }
        *(bf16x8*)&As[mo][ko] = t;
        *(bf16x8*)&Bs[mo][ko] = bf ? pw : cvt8(pw0, pw1);
    };

    f32x4 acc[4] = {};
    issue(0);
    commit(0);
    __syncthreads();
    int cur = 0;
    for (int k0 = 0; k0 < 512; k0 += 32) {
        const bool haveNext = (k0 + 32 < 512);
        if (haveNext) issue(k0 + 32);
        __bf16 (*As)[40] = (__bf16 (*)[40])sm[cur];
        __bf16 (*Bs)[40] = (__bf16 (*)[40])(sm[cur] + 64 * 40);
        const bf16x8 a = *(const bf16x8*)&As[wave * 16 + lm][kq * 8];
        #pragma unroll
        for (int nt = 0; nt < 4; ++nt) {
            const bf16x8 b = *(const bf16x8*)&Bs[nt * 16 + lm][kq * 8];
            acc[nt] = __builtin_amdgcn_mfma_f32_16x16x32_bf16(a, b, acc[nt], 0, 0, 0);
        }
        if (haveNext) {
            commit(cur ^ 1);
            __syncthreads();
            cur ^= 1;
        }
    }
    #pragma unroll
    for (int nt = 0; nt < 4; ++nt) {
        const int n = n0 + nt * 16 + lm;
        #pragma unroll
        for (int r2 = 0; r2 < 4; ++r2) {
            const int m = m0 + wave * 16 + kq * 4 + r2;
            float v = acc[nt][r2] + ldin(bo, (size_t)n, bf);
            stout(out, (size_t)m * 512 + n, bf, v);
        }
    }
}

extern "C" void kernel_launch(void* const* d_in, const int* in_sizes, int n_in,
                              void* d_out, int out_size, void* d_ws, size_t ws_size,
                              hipStream_t stream)
{
    const void* x   = d_in[0];
    const void* stf = d_in[1];
    const void* Mi  = d_in[2];
    const void* Mf  = d_in[3];
    const void* Wq  = d_in[4];  const void* bq = d_in[5];
    const void* Wk  = d_in[6];  const void* bk = d_in[7];
    const void* Wv  = d_in[8];  const void* bv = d_in[9];
    const void* Wg  = d_in[10]; const void* bg = d_in[11];
    const void* Wo  = d_in[12]; const void* bo = d_in[13];
    const void* lnw = d_in[14]; const void* lnb = d_in[15];

    float* base = (float*)d_ws;
    __bf16* f_u   = (__bf16*)base;               // u bf16 (2 MB)
    __bf16* f_phi = f_u + 1048576;               // phi bf16 (1 MB)
    float*  f_w   = base + 786432;               // conv accum fp32 (4 MB, zeroed)
    float*  f_T   = base + 1835008;              // attn tile-states fp32 (4 MB)
    __bf16* f_VT  = (__bf16*)(base + 2883584);   // V transposed [b][h][p][t] (2 MB)
    __bf16* f_Q   = (__bf16*)(base + 3407872);   // bf16 2048x512 (2 MB)
    __bf16* f_KT  = f_Q + 1048576;               // bf16 K transposed [b][h][p][t]
    __bf16* f_V   = f_KT + 1048576;
    __bf16* f_G   = f_V + 1048576;
    float*  f_st  = (float*)(f_G + 1048576);     // LN stats 2048 x {mu, rs} (16 KB)
    __bf16* f_Yb  = (__bf16*)(f_st + 4096);      // attn out bf16 (2 MB)
    // total ws: ~23 MB

    const int bf = (in_sizes[0] == BATCH * T_SEQ * D_MOD * 2);

    dim3 blk(256);

    // z=0 fused {Q,K}, z=1 fused {V,G}(+VT), z=2 job0, z=3 job5 + zero f_w
    if (bf)
        mega_gemm<1><<<dim3(8, 32, 4), blk, 0, stream>>>(
            x, Mi, stf, Mf, Wq, bq, Wk, bk, Wv, bv, Wg, bg,
            f_u, f_phi, f_Q, f_KT, f_V, f_VT, f_G);
    else
        mega_gemm<0><<<dim3(8, 32, 4), blk, 0, stream>>>(
            x, Mi, stf, Mf, Wq, bq, Wk, bk, Wv, bv, Wg, bg,
            f_u, f_phi, f_Q, f_KT, f_V, f_VT, f_G);

    state_k<<<dim3(16, 8, 2), blk, 0, stream>>>(f_KT, f_VT, f_T);

    conv_attn_k<<<dim3(40, 8, 4), blk, 0, stream>>>(f_u, f_phi, f_w, f_Q, f_KT, f_V, f_T, f_Yb);

    stats_k<<<dim3(128), blk, 0, stream>>>(f_w, f_st);

    if (bf) final_gemm<1><<<dim3(8, 32), blk, 0, stream>>>(f_G, f_Yb, f_w, f_st, lnw, lnb, Wo, bo, d_out);
    else    final_gemm<0><<<dim3(8, 32), blk, 0, stream>>>(f_G, f_Yb, f_w, f_st, lnw, lnb, Wo, bo, d_out);
}

// Round 9
// 165.830 us; speedup vs baseline: 1.0115x; 1.0115x over previous
//
#include <hip/hip_runtime.h>
#include <hip/hip_bf16.h>

#define T_SEQ 1024
#define D_MOD 512
#define NHEAD 8
#define HDIM  64
#define R_DIM 512
#define BATCH 2

typedef __attribute__((ext_vector_type(8))) __bf16 bf16x8;
typedef __attribute__((ext_vector_type(4))) __bf16 bf16x4;
typedef __attribute__((ext_vector_type(4))) float f32x4;
typedef __attribute__((ext_vector_type(2))) float f32x2;

__device__ __forceinline__ float ldin(const void* p, size_t i, int bf) {
    if (bf) return __bfloat162float(((const __hip_bfloat16*)p)[i]);
    return ((const float*)p)[i];
}
__device__ __forceinline__ void stout(void* p, size_t i, int bf, float v) {
    if (bf) ((__hip_bfloat16*)p)[i] = __float2bfloat16(v);
    else    ((float*)p)[i] = v;
}

__device__ __forceinline__ float gelu_f(float x) {
    return 0.5f * x * (1.f + tanhf(0.7978845608028654f * (x + 0.044715f * x * x * x)));
}

__device__ __forceinline__ bf16x8 cvt8(float4 a, float4 b) {
    bf16x8 t;
    t[0]=(__bf16)a.x; t[1]=(__bf16)a.y; t[2]=(__bf16)a.z; t[3]=(__bf16)a.w;
    t[4]=(__bf16)b.x; t[5]=(__bf16)b.y; t[6]=(__bf16)b.z; t[7]=(__bf16)b.w;
    return t;
}

// ---------------- fused projection GEMMs + zero job (R7/R8, unchanged) -------
template<int BF>
__global__ __launch_bounds__(256) void mega_gemm(
    const void* __restrict__ x, const void* __restrict__ Mi,
    const void* __restrict__ stf, const void* __restrict__ Mf,
    const void* __restrict__ Wq, const void* __restrict__ bq,
    const void* __restrict__ Wk, const void* __restrict__ bk,
    const void* __restrict__ Wv, const void* __restrict__ bv,
    const void* __restrict__ Wg, const void* __restrict__ bg,
    __bf16* __restrict__ fu, __bf16* __restrict__ fphi,
    __bf16* __restrict__ fQ, __bf16* __restrict__ fKT,
    __bf16* __restrict__ fV, __bf16* __restrict__ fVT,
    __bf16* __restrict__ fG)
{
    constexpr int bf = BF;
    const int tid = threadIdx.x;
    const int z = blockIdx.z;
    const int m0 = blockIdx.y * 64;
    const int n0 = blockIdx.x * 64;

    __shared__ __align__(16) __bf16 As[64][40];
    __shared__ __align__(16) __bf16 Bs[2][64][40];
    const int wave = tid >> 6, lane = tid & 63;
    const int lm = lane & 15, kq = lane >> 4;
    const int mo = tid >> 2, ko = (tid & 3) * 8;

    if (z <= 1) {
        const void* Wp0 = (z == 0) ? Wq : Wv;
        const void* Wp1 = (z == 0) ? Wk : Wg;
        const void* bp0 = (z == 0) ? bq : bv;
        const void* bp1 = (z == 0) ? bk : bg;
        f32x4 acc[2][4] = {};
        const int cs = ((((ko >> 3) ^ (mo >> 3)) & 3) << 3);

        for (int k0 = 0; k0 < 512; k0 += 32) {
            if (k0) __syncthreads();
            if (bf) {
                *(bf16x8*)&As[mo][ko] =
                    *(const bf16x8*)((const __bf16*)x + (size_t)(m0 + mo) * 512 + k0 + ko);
            } else {
                const float* Af = (const float*)x + (size_t)(m0 + mo) * 512 + k0 + ko;
                *(bf16x8*)&As[mo][ko] = cvt8(*(const float4*)Af, *(const float4*)(Af + 4));
            }
            const size_t go = (size_t)(n0 + mo) * 512 + k0 + ko;
            if (bf) {
                *(bf16x8*)&Bs[0][mo][cs] = *(const bf16x8*)((const __bf16*)Wp0 + go);
                *(bf16x8*)&Bs[1][mo][cs] = *(const bf16x8*)((const __bf16*)Wp1 + go);
            } else {
                const float* B0 = (const float*)Wp0 + go;
                const float* B1 = (const float*)Wp1 + go;
                *(bf16x8*)&Bs[0][mo][cs] = cvt8(*(const float4*)B0, *(const float4*)(B0 + 4));
                *(bf16x8*)&Bs[1][mo][cs] = cvt8(*(const float4*)B1, *(const float4*)(B1 + 4));
            }
            __syncthreads();
            const bf16x8 a = *(const bf16x8*)&As[wave * 16 + lm][kq * 8];
            #pragma unroll
            for (int p = 0; p < 2; ++p) {
                #pragma unroll
                for (int nt = 0; nt < 4; ++nt) {
                    const int row = nt * 16 + lm;
                    const bf16x8 b = *(const bf16x8*)&Bs[p][row][(((kq ^ (row >> 3)) & 3) << 3)];
                    acc[p][nt] = __builtin_amdgcn_mfma_f32_16x16x32_bf16(a, b, acc[p][nt], 0, 0, 0);
                }
            }
        }
        #pragma unroll
        for (int p = 0; p < 2; ++p) {
            const void* bias = p ? bp1 : bp0;
            #pragma unroll
            for (int nt = 0; nt < 4; ++nt) {
                const int n = n0 + nt * 16 + lm;
                #pragma unroll
                for (int r2 = 0; r2 < 4; ++r2) {
                    const int m = m0 + wave * 16 + kq * 4 + r2;
                    float v = acc[p][nt][r2] + ldin(bias, (size_t)n, bf);
                    v = (z == 1 && p == 1) ? 1.f / (1.f + expf(-v)) : gelu_f(v);
                    const int b = m >> 10, t = m & 1023;
                    const int h = n >> 6,  pp = n & 63;
                    if (z == 0) {
                        if (p == 0) fQ[(size_t)m * 512 + n] = (__bf16)v;
                        else fKT[(((size_t)b * NHEAD + h) * 64 + pp) * T_SEQ + t] = (__bf16)v;
                    } else {
                        if (p == 0) {
                            fV[(size_t)m * 512 + n] = (__bf16)v;
                            fVT[(((size_t)b * NHEAD + h) * 64 + pp) * T_SEQ + t] = (__bf16)v;
                        } else {
                            fG[(size_t)m * 512 + n] = (__bf16)v;
                        }
                    }
                }
            }
        }
    } else if (z == 2) {
        // ---- job0: fu = x @ Mi ----
        f32x4 acc[4] = {};
        const int kk = tid >> 3, nn = (tid & 7) * 8;
        for (int k0 = 0; k0 < 512; k0 += 32) {
            if (k0) __syncthreads();
            if (bf) {
                *(bf16x8*)&As[mo][ko] =
                    *(const bf16x8*)((const __bf16*)x + (size_t)(m0 + mo) * 512 + k0 + ko);
            } else {
                const float* Af = (const float*)x + (size_t)(m0 + mo) * 512 + k0 + ko;
                *(bf16x8*)&As[mo][ko] = cvt8(*(const float4*)Af, *(const float4*)(Af + 4));
            }
            {
                const size_t off = (size_t)(k0 + kk) * 512 + n0 + nn;
                bf16x8 t;
                if (bf) {
                    t = *(const bf16x8*)((const __bf16*)Mi + off);
                } else {
                    const float* Bf = (const float*)Mi + off;
                    t = cvt8(*(const float4*)Bf, *(const float4*)(Bf + 4));
                }
                #pragma unroll
                for (int q = 0; q < 8; ++q) {
                    const int row = nn + q;
                    const int c = ((((kk >> 3) ^ (row >> 3)) & 3) << 3) | (kk & 7);
                    Bs[0][row][c] = t[q];
                }
            }
            __syncthreads();
            const bf16x8 a = *(const bf16x8*)&As[wave * 16 + lm][kq * 8];
            #pragma unroll
            for (int nt = 0; nt < 4; ++nt) {
                const int row = nt * 16 + lm;
                const bf16x8 b = *(const bf16x8*)&Bs[0][row][(((kq ^ (row >> 3)) & 3) << 3)];
                acc[nt] = __builtin_amdgcn_mfma_f32_16x16x32_bf16(a, b, acc[nt], 0, 0, 0);
            }
        }
        #pragma unroll
        for (int nt = 0; nt < 4; ++nt) {
            const int n = n0 + nt * 16 + lm;
            #pragma unroll
            for (int r2 = 0; r2 < 4; ++r2) {
                const int m = m0 + wave * 16 + kq * 4 + r2;
                fu[(size_t)m * 512 + n] = (__bf16)acc[nt][r2];
            }
        }
    } else {
        if (blockIdx.y >= 16) {
            // ---- zero f_w (4 MB) ----
            float4* zp = (float4*)(fphi + 524288);           // == f_w
            const int bid = (blockIdx.y - 16) * 8 + blockIdx.x;   // 0..127
            const float4 z4 = make_float4(0.f, 0.f, 0.f, 0.f);
            #pragma unroll
            for (int q = 0; q < 8; ++q)
                zp[(size_t)bid * 2048 + q * 256 + tid] = z4;
            return;
        }
        // ---- job5: fphi = stf @ Mf ----
        f32x4 acc[4] = {};
        const int kk = tid >> 3, nn = (tid & 7) * 8;
        {
            bf16x8 t;
            #pragma unroll
            for (int q = 0; q < 8; ++q) {
                const int k = ko + q;
                t[q] = (k < 24) ? (__bf16)ldin(stf, (size_t)(m0 + mo) * 24 + k, bf)
                                : (__bf16)0.f;
            }
            *(bf16x8*)&As[mo][ko] = t;
        }
        #pragma unroll
        for (int q = 0; q < 8; ++q) {
            const int row = nn + q;
            const int c = ((((kk >> 3) ^ (row >> 3)) & 3) << 3) | (kk & 7);
            Bs[0][row][c] = (kk < 24) ? (__bf16)ldin(Mf, (size_t)kk * 512 + n0 + row, bf)
                                      : (__bf16)0.f;
        }
        __syncthreads();
        const bf16x8 a = *(const bf16x8*)&As[wave * 16 + lm][kq * 8];
        #pragma unroll
        for (int nt = 0; nt < 4; ++nt) {
            const int row = nt * 16 + lm;
            const bf16x8 b = *(const bf16x8*)&Bs[0][row][(((kq ^ (row >> 3)) & 3) << 3)];
            acc[nt] = __builtin_amdgcn_mfma_f32_16x16x32_bf16(a, b, acc[nt], 0, 0, 0);
        }
        #pragma unroll
        for (int nt = 0; nt < 4; ++nt) {
            const int n = n0 + nt * 16 + lm;
            #pragma unroll
            for (int r2 = 0; r2 < 4; ++r2) {
                const int m = m0 + wave * 16 + kq * 4 + r2;
                fphi[(size_t)m * 512 + n] = (__bf16)acc[nt][r2];
            }
        }
    }
}

// ---------------- conv + linear-attention with INLINED prefix state ----------
// R9: state_k folded in. Each attention block (b,h,ti) accumulates its own
// prefix P in registers by staging K^T/V^T tiles j<ti from L2 (state_k's
// exact MFMA pattern), then Y = masked(QV^T)K + Q*P. Removes the state_k
// launch + the f_T 4MB write/30MB read round-trip.
__global__ __launch_bounds__(256) void conv_attn_k(
    const __bf16* __restrict__ u, const __bf16* __restrict__ vphi,
    float* __restrict__ w,
    const __bf16* __restrict__ Q, const __bf16* __restrict__ KT,
    const __bf16* __restrict__ V, const __bf16* __restrict__ VT,
    __bf16* __restrict__ Yb)
{
    __shared__ __align__(16) unsigned char smem[49152];
    const int tid = threadIdx.x;
    const int z = blockIdx.z;

    if (z < 2) {
        int rem = blockIdx.x, ti = 0;
        while (rem >= ((ti + 4) >> 2)) { rem -= (ti + 4) >> 2; ++ti; }
        const int jlo = rem * 4;
        const int jhi = (jlo + 3 < ti) ? jlo + 3 : ti;
        const int t0 = ti * 64;
        float (*vs)[64] = (float (*)[64])smem;            // 16 KB
        float (*us)[64] = (float (*)[64])(smem + 16384);  // 32 KB
        const int rl = tid & 63, tg = tid >> 6;
        const int b = z;
        const int r0 = blockIdx.y * 64;
        const __bf16* ub = u + (size_t)b * T_SEQ * R_DIM;
        f32x2 acc2[8] = {};
        for (int j = jlo; j <= jhi; ++j) {
            if (j != jlo) __syncthreads();
            const int L0 = j * 64;
            const int W0 = t0 - L0 - 63;
            #pragma unroll
            for (int jj = 0; jj < 8; ++jj) {
                const int n = jj * 256 + tid;
                const int row = n >> 4, c4 = (n & 15) * 4;
                int s = W0 + row;
                s = s < 0 ? 0 : (s > T_SEQ - 1 ? T_SEQ - 1 : s);
                const bf16x4 t = *(const bf16x4*)&ub[(size_t)s * R_DIM + r0 + c4];
                *(float4*)&us[row][c4] =
                    make_float4((float)t[0], (float)t[1], (float)t[2], (float)t[3]);
            }
            #pragma unroll
            for (int jj = 0; jj < 4; ++jj) {
                const int n = jj * 256 + tid;
                const int row = n >> 4, c4 = (n & 15) * 4;
                const bf16x4 t = *(const bf16x4*)&vphi[(size_t)(L0 + row) * R_DIM + r0 + c4];
                *(float4*)&vs[row][c4] =
                    make_float4((float)t[0], (float)t[1], (float)t[2], (float)t[3]);
            }
            __syncthreads();
            if (j < ti) {
                #pragma unroll
                for (int g = 0; g < 4; ++g) {
                    const int wsmin = tg * 16 + 49 - 16 * g;
                    f32x2 ur2[15];
                    #pragma unroll
                    for (int m = 0; m < 15; ++m) {
                        ur2[m][0] = us[wsmin + 2 * m][rl];
                        ur2[m][1] = us[wsmin + 2 * m + 1][rl];
                    }
                    float vr[8];
                    #pragma unroll
                    for (int e = 0; e < 8; ++e) vr[e] = vs[16 * g + 2 * e][rl];
                    #pragma unroll
                    for (int e = 0; e < 8; ++e) {
                        f32x2 vv2; vv2[0] = vr[e]; vv2[1] = vr[e];
                        #pragma unroll
                        for (int jj = 0; jj < 8; ++jj)
                            asm("v_pk_fma_f32 %0, %1, %2, %0"
                                : "+v"(acc2[jj]) : "v"(ur2[jj - e + 7]), "v"(vv2));
                    }
                }
            } else {
                for (int l = 0; l < 64; l += 2) {
                    const float vv = vs[l][rl];
                    #pragma unroll
                    for (int i = 0; i < 16; ++i) {
                        const int srel = tg * 16 + i - l;
                        if (srel >= 0) acc2[i >> 1][i & 1] += vv * us[srel + 63][rl];
                    }
                }
            }
        }
        #pragma unroll
        for (int i = 0; i < 16; ++i)
            atomicAdd(&w[((size_t)b * T_SEQ + t0 + tg * 16 + i) * R_DIM + r0 + rl],
                      2.f * acc2[i >> 1][i & 1]);
    } else {
        const int ti = blockIdx.x;
        if (ti >= 16) return;
        const int t0 = ti * 64;
        __bf16 (*Qs)[72] = (__bf16 (*)[72])smem;
        __bf16 (*Vs)[72] = (__bf16 (*)[72])(smem + 9216);
        __bf16 (*Kt)[72] = (__bf16 (*)[72])(smem + 18432);
        __bf16 (*Sa)[72] = (__bf16 (*)[72])(smem + 27648);   // also Kj staging
        __bf16 (*PB)[72] = (__bf16 (*)[72])(smem + 36864);   // also Vj staging
        const int wave = tid >> 6, lane = tid & 63;
        const int lm = lane & 15, kq = lane >> 4;
        const int b = z - 2;
        const int h = blockIdx.y;
        const size_t hb = (size_t)b * NHEAD + h;
        const size_t cbase = ((size_t)b * T_SEQ) * D_MOD + h * HDIM;
        const __bf16* KTh = KT + hb * 64 * T_SEQ;
        const __bf16* VTh = VT + hb * 64 * T_SEQ;

        // stage Q, V (own tile, row-major), K^T (own tile)
        #pragma unroll
        for (int it = 0; it < 2; ++it) {
            const int n = it * 256 + tid;
            const int row = n >> 3, c0 = (n & 7) * 8;
            *(bf16x8*)&Qs[row][c0] = *(const bf16x8*)&Q[cbase + (size_t)(t0 + row) * D_MOD + c0];
            *(bf16x8*)&Vs[row][c0] = *(const bf16x8*)&V[cbase + (size_t)(t0 + row) * D_MOD + c0];
            *(bf16x8*)&Kt[row][c0] = *(const bf16x8*)&KTh[(size_t)row * T_SEQ + t0 + c0];
        }
        // prefix-state in registers: pacc[n][p] = sum_{j<ti} sum_s K[s][n]V[s][p]
        f32x4 pacc[4] = {};
        for (int j = 0; j < ti; ++j) {
            __syncthreads();
            const int s0 = j * 64;
            #pragma unroll
            for (int it = 0; it < 2; ++it) {
                const int n = it * 256 + tid;
                const int row = n >> 3, c0 = (n & 7) * 8;
                *(bf16x8*)&Sa[row][c0] = *(const bf16x8*)&KTh[(size_t)row * T_SEQ + s0 + c0];
                *(bf16x8*)&PB[row][c0] = *(const bf16x8*)&VTh[(size_t)row * T_SEQ + s0 + c0];
            }
            __syncthreads();
            #pragma unroll
            for (int ks = 0; ks < 2; ++ks) {
                const bf16x8 a = *(const bf16x8*)&Sa[wave * 16 + lm][ks * 32 + kq * 8];
                #pragma unroll
                for (int nt = 0; nt < 4; ++nt) {
                    const bf16x8 bb = *(const bf16x8*)&PB[nt * 16 + lm][ks * 32 + kq * 8];
                    pacc[nt] = __builtin_amdgcn_mfma_f32_16x16x32_bf16(a, bb, pacc[nt], 0, 0, 0);
                }
            }
        }
        __syncthreads();   // staging visible (ti==0 case) + last prefix MFMA reads done
        // PB[n][p] = pacc  (same layout/consumption as R7/R8 -- verified correct)
        #pragma unroll
        for (int nt = 0; nt < 4; ++nt) {
            const int p = nt * 16 + lm;
            #pragma unroll
            for (int r2 = 0; r2 < 4; ++r2)
                PB[wave * 16 + kq * 4 + r2][p] = (__bf16)pacc[nt][r2];
        }

        // S = causal-masked Q V^T (wave-local rows -> no barrier before reuse)
        f32x4 sacc[4] = {};
        #pragma unroll
        for (int ks = 0; ks < 2; ++ks) {
            const bf16x8 a = *(const bf16x8*)&Qs[wave * 16 + lm][ks * 32 + kq * 8];
            #pragma unroll
            for (int nt = 0; nt < 4; ++nt) {
                const bf16x8 bb = *(const bf16x8*)&Vs[nt * 16 + lm][ks * 32 + kq * 8];
                sacc[nt] = __builtin_amdgcn_mfma_f32_16x16x32_bf16(a, bb, sacc[nt], 0, 0, 0);
            }
        }
        #pragma unroll
        for (int nt = 0; nt < 4; ++nt) {
            const int sl = nt * 16 + lm;
            #pragma unroll
            for (int r2 = 0; r2 < 4; ++r2) {
                const int tl = wave * 16 + kq * 4 + r2;
                float v = sacc[nt][r2];
                if (sl > tl) v = 0.f;
                Sa[tl][sl] = (__bf16)v;
            }
        }
        // Y1 = Sa * K
        f32x4 accY[4] = {};
        #pragma unroll
        for (int ks = 0; ks < 2; ++ks) {
            const bf16x8 a = *(const bf16x8*)&Sa[wave * 16 + lm][ks * 32 + kq * 8];
            #pragma unroll
            for (int nt = 0; nt < 4; ++nt) {
                const bf16x8 bb = *(const bf16x8*)&Kt[nt * 16 + lm][ks * 32 + kq * 8];
                accY[nt] = __builtin_amdgcn_mfma_f32_16x16x32_bf16(a, bb, accY[nt], 0, 0, 0);
            }
        }
        __syncthreads();   // PB writes visible to all waves before Y2
        // Y2 += Q * P
        if (ti) {
            #pragma unroll
            for (int ks = 0; ks < 2; ++ks) {
                const bf16x8 a = *(const bf16x8*)&Qs[wave * 16 + lm][ks * 32 + kq * 8];
                #pragma unroll
                for (int nt = 0; nt < 4; ++nt) {
                    const bf16x8 bb = *(const bf16x8*)&PB[nt * 16 + lm][ks * 32 + kq * 8];
                    accY[nt] = __builtin_amdgcn_mfma_f32_16x16x32_bf16(a, bb, accY[nt], 0, 0, 0);
                }
            }
        }
        #pragma unroll
        for (int nt = 0; nt < 4; ++nt) {
            const int nh = nt * 16 + lm;
            #pragma unroll
            for (int r2 = 0; r2 < 4; ++r2) {
                const int tl = wave * 16 + kq * 4 + r2;
                Yb[cbase + (size_t)(t0 + tl) * D_MOD + nh] = (__bf16)accY[nt][r2];
            }
        }
    }
}

// ---------------- LN row stats (unchanged) ----------
__global__ __launch_bounds__(256) void stats_k(const float* __restrict__ w,
                                               float* __restrict__ stats)
{
    const int tid = threadIdx.x;
    const int r = tid >> 4, c = tid & 15;
    const int row = blockIdx.x * 16 + r;
    const float* p = w + (size_t)row * R_DIM;
    float s = 0.f, ss = 0.f;
    #pragma unroll
    for (int q = 0; q < 8; ++q) {
        const float4 v = *(const float4*)(p + c * 4 + q * 64);
        s  += v.x + v.y + v.z + v.w;
        ss += v.x * v.x + v.y * v.y + v.z * v.z + v.w * v.w;
    }
    s  += __shfl_xor(s, 1, 64);  s  += __shfl_xor(s, 2, 64);
    s  += __shfl_xor(s, 4, 64);  s  += __shfl_xor(s, 8, 64);
    ss += __shfl_xor(ss, 1, 64); ss += __shfl_xor(ss, 2, 64);
    ss += __shfl_xor(ss, 4, 64); ss += __shfl_xor(ss, 8, 64);
    if (c == 0) {
        const float mu = s * (1.f / 512.f);
        float var = ss * (1.f / 512.f) - mu * mu;
        var = var < 0.f ? 0.f : var;
        stats[row * 2]     = mu;
        stats[row * 2 + 1] = rsqrtf(var + 1e-5f);
    }
}

// ---------------- final GEMM with fused LN + comb (unchanged) ----------------
template<int BF>
__global__ __launch_bounds__(256) void final_gemm(const __bf16* __restrict__ G,
                                                  const __bf16* __restrict__ Yf,
                                                  const float* __restrict__ Wf,
                                                  const float* __restrict__ stats,
                                                  const void* __restrict__ lnw,
                                                  const void* __restrict__ lnb,
                                                  const void* __restrict__ Wo,
                                                  const void* __restrict__ bo,
                                                  void* __restrict__ out)
{
    constexpr int bf = BF;
    __shared__ __align__(16) __bf16 sm[2][2 * 64 * 40];
    const int tid = threadIdx.x;
    const int wave = tid >> 6, lane = tid & 63;
    const int lm = lane & 15, kq = lane >> 4;
    const int mo = tid >> 2, ko = (tid & 3) * 8;
    const int m0 = blockIdx.y * 64, n0 = blockIdx.x * 64;

    const float2 st = *(const float2*)(stats + (size_t)(m0 + mo) * 2);
    const float mu = st.x, rs = st.y;

    bf16x8 pg, py, pw, pLg, pLb;
    float4 pv0, pv1, pw0, pw1, pLg0, pLg1, pLb0, pLb1;

    auto issue = [&](int k0) {
        const size_t off = (size_t)(m0 + mo) * 512 + k0 + ko;
        pg  = *(const bf16x8*)(G + off);
        py  = *(const bf16x8*)(Yf + off);
        pv0 = *(const float4*)(Wf + off); pv1 = *(const float4*)(Wf + off + 4);
        const size_t ob = (size_t)(n0 + mo) * 512 + k0 + ko;
        if (bf) {
            pw  = *(const bf16x8*)((const __bf16*)Wo + ob);
            pLg = *(const bf16x8*)((const __bf16*)lnw + k0 + ko);
            pLb = *(const bf16x8*)((const __bf16*)lnb + k0 + ko);
        } else {
            const float* Bf = (const float*)Wo + ob;
            pw0 = *(const float4*)Bf; pw1 = *(const float4*)(Bf + 4);
            const float* Lg = (const float*)lnw + k0 + ko;
            pLg0 = *(const float4*)Lg; pLg1 = *(const float4*)(Lg + 4);
            const float* Lb = (const float*)lnb + k0 + ko;
            pLb0 = *(const float4*)Lb; pLb1 = *(const float4*)(Lb + 4);
        }
    };
    auto commit = [&](int bi) {
        __bf16 (*As)[40] = (__bf16 (*)[40])sm[bi];
        __bf16 (*Bs)[40] = (__bf16 (*)[40])(sm[bi] + 64 * 40);
        const float wv[8] = {pv0.x,pv0.y,pv0.z,pv0.w,pv1.x,pv1.y,pv1.z,pv1.w};
        float gw[8], gb[8];
        if (bf) {
            #pragma unroll
            for (int q = 0; q < 8; ++q) { gw[q] = (float)pLg[q]; gb[q] = (float)pLb[q]; }
        } else {
            gw[0]=pLg0.x; gw[1]=pLg0.y; gw[2]=pLg0.z; gw[3]=pLg0.w;
            gw[4]=pLg1.x; gw[5]=pLg1.y; gw[6]=pLg1.z; gw[7]=pLg1.w;
            gb[0]=pLb0.x; gb[1]=pLb0.y; gb[2]=pLb0.z; gb[3]=pLb0.w;
            gb[4]=pLb1.x; gb[5]=pLb1.y; gb[6]=pLb1.z; gb[7]=pLb1.w;
        }
        bf16x8 t;
        #pragma unroll
        for (int q = 0; q < 8; ++q) {
            const float xt = (wv[q] - mu) * rs * gw[q] + gb[q];
            const float gg = (float)pg[q];
            t[q] = (__bf16)(gg * (float)py[q] + (1.f - gg) * xt);
        }
        *(bf16x8*)&As[mo][ko] = t;
        *(bf16x8*)&Bs[mo][ko] = bf ? pw : cvt8(pw0, pw1);
    };

    f32x4 acc[4] = {};
    issue(0);
    commit(0);
    __syncthreads();
    int cur = 0;
    for (int k0 = 0; k0 < 512; k0 += 32) {
        const bool haveNext = (k0 + 32 < 512);
        if (haveNext) issue(k0 + 32);
        __bf16 (*As)[40] = (__bf16 (*)[40])sm[cur];
        __bf16 (*Bs)[40] = (__bf16 (*)[40])(sm[cur] + 64 * 40);
        const bf16x8 a = *(const bf16x8*)&As[wave * 16 + lm][kq * 8];
        #pragma unroll
        for (int nt = 0; nt < 4; ++nt) {
            const bf16x8 b = *(const bf16x8*)&Bs[nt * 16 + lm][kq * 8];
            acc[nt] = __builtin_amdgcn_mfma_f32_16x16x32_bf16(a, b, acc[nt], 0, 0, 0);
        }
        if (haveNext) {
            commit(cur ^ 1);
            __syncthreads();
            cur ^= 1;
        }
    }
    #pragma unroll
    for (int nt = 0; nt < 4; ++nt) {
        const int n = n0 + nt * 16 + lm;
        #pragma unroll
        for (int r2 = 0; r2 < 4; ++r2) {
            const int m = m0 + wave * 16 + kq * 4 + r2;
            float v = acc[nt][r2] + ldin(bo, (size_t)n, bf);
            stout(out, (size_t)m * 512 + n, bf, v);
        }
    }
}

extern "C" void kernel_launch(void* const* d_in, const int* in_sizes, int n_in,
                              void* d_out, int out_size, void* d_ws, size_t ws_size,
                              hipStream_t stream)
{
    const void* x   = d_in[0];
    const void* stf = d_in[1];
    const void* Mi  = d_in[2];
    const void* Mf  = d_in[3];
    const void* Wq  = d_in[4];  const void* bq = d_in[5];
    const void* Wk  = d_in[6];  const void* bk = d_in[7];
    const void* Wv  = d_in[8];  const void* bv = d_in[9];
    const void* Wg  = d_in[10]; const void* bg = d_in[11];
    const void* Wo  = d_in[12]; const void* bo = d_in[13];
    const void* lnw = d_in[14]; const void* lnb = d_in[15];

    float* base = (float*)d_ws;
    __bf16* f_u   = (__bf16*)base;               // u bf16 (2 MB)
    __bf16* f_phi = f_u + 1048576;               // phi bf16 (1 MB)
    float*  f_w   = base + 786432;               // conv accum fp32 (4 MB, zeroed)
    __bf16* f_VT  = (__bf16*)(base + 2883584);   // V transposed [b][h][p][t] (2 MB)
    __bf16* f_Q   = (__bf16*)(base + 3407872);   // bf16 2048x512 (2 MB)
    __bf16* f_KT  = f_Q + 1048576;               // bf16 K transposed [b][h][p][t]
    __bf16* f_V   = f_KT + 1048576;
    __bf16* f_G   = f_V + 1048576;
    float*  f_st  = (float*)(f_G + 1048576);     // LN stats 2048 x {mu, rs} (16 KB)
    __bf16* f_Yb  = (__bf16*)(f_st + 4096);      // attn out bf16 (2 MB)
    // total ws: ~23 MB

    const int bf = (in_sizes[0] == BATCH * T_SEQ * D_MOD * 2);

    dim3 blk(256);

    // z=0 fused {Q,K}, z=1 fused {V,G}(+VT), z=2 job0, z=3 job5 + zero f_w
    if (bf)
        mega_gemm<1><<<dim3(8, 32, 4), blk, 0, stream>>>(
            x, Mi, stf, Mf, Wq, bq, Wk, bk, Wv, bv, Wg, bg,
            f_u, f_phi, f_Q, f_KT, f_V, f_VT, f_G);
    else
        mega_gemm<0><<<dim3(8, 32, 4), blk, 0, stream>>>(
            x, Mi, stf, Mf, Wq, bq, Wk, bk, Wv, bv, Wg, bg,
            f_u, f_phi, f_Q, f_KT, f_V, f_VT, f_G);

    conv_attn_k<<<dim3(40, 8, 4), blk, 0, stream>>>(f_u, f_phi, f_w, f_Q, f_KT, f_V, f_VT, f_Yb);

    stats_k<<<dim3(128), blk, 0, stream>>>(f_w, f_st);

    if (bf) final_gemm<1><<<dim3(8, 32), blk, 0, stream>>>(f_G, f_Yb, f_w, f_st, lnw, lnb, Wo, bo, d_out);
    else    final_gemm<0><<<dim3(8, 32), blk, 0, stream>>>(f_G, f_Yb, f_w, f_st, lnw, lnb, Wo, bo, d_out);
}